// Round 8
// baseline (1163.704 us; speedup 1.0000x reference)
//
#include <hip/hip_runtime.h>
#include <hip/hip_bf16.h>
#include <math.h>
#include <stdint.h>

// ---------------- types & helpers ----------------
typedef __attribute__((ext_vector_type(8))) short short8;   // 8 x bf16 (MFMA A/B frag)
typedef __attribute__((ext_vector_type(4))) float floatx4;  // MFMA C/D frag

#define DEVI __device__ __forceinline__

DEVI float b2f(unsigned short u) {
    union { unsigned int i; float f; } v; v.i = ((unsigned int)u) << 16; return v.f;
}
DEVI unsigned short f2b(float f) {   // RNE f32 -> bf16
    unsigned int x = __float_as_uint(f);
    unsigned int r = (x + 0x7fffu + ((x >> 16) & 1u)) >> 16;
    return (unsigned short)r;
}

// global -> LDS direct (16B per lane). LDS dest must be wave-uniform base + lane*16.
#define GLD16(gp, lp)                                                            \
    __builtin_amdgcn_global_load_lds(                                            \
        (__attribute__((address_space(1))) unsigned int*)(gp),                   \
        (__attribute__((address_space(3))) unsigned int*)(lp), 16, 0, 0)

static constexpr int NQ = 4096, NS = 16384;
static constexpr int NROW_Q = 4 * NQ;   // 16384 query rows
static constexpr int NROW_S = 4 * NS;   // 65536 source rows
static constexpr int NQH = 8192;        // queries per half (de-fused attn path)
static constexpr float INV2PI = 0.15915494309189535f;

// ---------------- prep: transpose weights to bf16 [N][K], penc0 ----------------
__global__ void k_prep(const float* Wproj, const float* saWv, const float* saWo,
                       const float* caWq, const float* caWk, const float* caWv,
                       const float* caWo, const float* W1, const float* W2,
                       const float* b_pos,
                       unsigned short* wTproj, unsigned short* wTsaWv, unsigned short* wTsaWo,
                       unsigned short* wTcaWq, unsigned short* wTkv, unsigned short* wTcaWo,
                       unsigned short* wTW1, unsigned short* wTW2, float* penc0)
{
    int z = blockIdx.z;
    if (z == 9) {   // penc0[c] = pos_enc(0): [0,0,0, cos(b_pos)]
        if (blockIdx.x == 0 && blockIdx.y == 0) {
            int c = threadIdx.y * 16 + threadIdx.x;
            float v = 0.f;
            if (c >= 3) {
                float rev = b_pos[c - 3] * INV2PI;
                rev -= floorf(rev);
                v = __builtin_amdgcn_cosf(rev);
            }
            penc0[c] = v;
        }
        return;
    }
    int n = blockIdx.x * 16 + threadIdx.x;   // output row (orig col)
    int k = blockIdx.y * 16 + threadIdx.y;   // output col (orig row)
    const float* src; unsigned short* dst; int K = 256;
    switch (z) {
        case 0: src = Wproj; dst = wTproj; K = 128; break;
        case 1: src = saWv;  dst = wTsaWv; break;
        case 2: src = saWo;  dst = wTsaWo; break;
        case 3: src = caWq;  dst = wTcaWq; break;
        case 4: src = caWk;  dst = wTkv;   break;
        case 5: src = caWv;  dst = wTkv + 256 * 256; break;
        case 6: src = caWo;  dst = wTcaWo; break;
        case 7: src = W1;    dst = wTW1;   break;
        default: src = W2;   dst = wTW2;   break;
    }
    if (k < K) dst[(size_t)n * K + k] = f2b(src[(size_t)k * 256 + n]);
}

// scale b_pos by 1/2pi (W_pos must stay UNSCALED: revolutions = x.W + b/2pi)
__global__ void k_scale(const float* b_pos, float* bp2)
{
    int i = blockIdx.x * blockDim.x + threadIdx.x;
    if (i < 253) bp2[i] = b_pos[i] * INV2PI;
}

// ---------------- f32 -> bf16 convert ----------------
__global__ void k_cvt(const float* in, unsigned short* out, int n4)
{
    int i = blockIdx.x * blockDim.x + threadIdx.x;
    int stride = gridDim.x * blockDim.x;
    for (; i < n4; i += stride) {
        float4 v = ((const float4*)in)[i];
        unsigned long long p =
              (unsigned long long)f2b(v.x)
            | ((unsigned long long)f2b(v.y) << 16)
            | ((unsigned long long)f2b(v.z) << 32)
            | ((unsigned long long)f2b(v.w) << 48);
        ((unsigned long long*)out)[i] = p;
    }
}

// ---------------- MFMA GEMM: out[M][N] = A[M][K](bf16) @ BT[N][K]^T + epilogue ----------------
// EPI: 0 = bf16 out, +bias            1 = bf16 out, +bias, relu
//      2 = f32 out, +bias +extra[col] 3 = f32 out, +bias +extra[row,col]
//      4 = f32 out, +bias +extra[row,col], nan_to_num
template<int EPI>
__global__ __launch_bounds__(256, 2)
void k_gemm(const unsigned short* A, const unsigned short* BT, const float* bias,
            const float* extra, void* outp, int M, int N, int K)
{
    __shared__ alignas(16) unsigned short lA[128 * 64];  // [128 rows][64 k], swizzled
    __shared__ alignas(16) unsigned short lB[64 * 64];   // [64 rows][64 k], swizzled
    const int tid = threadIdx.x;
    const int wave = tid >> 6, lane = tid & 63;
    const int m0 = blockIdx.x * 128, n0 = blockIdx.y * 64;
    const int wm = (wave >> 1) * 64, wn = (wave & 1) * 32;
    floatx4 acc[4][2] = {};

    for (int kt = 0; kt < K; kt += 64) {
        __syncthreads();
        #pragma unroll
        for (int c = 0; c < 4; ++c) {   // stage A tile 16KB
            int o = (tid + c * 256) * 16;
            int row = o >> 7, inner = o & 127;
            int srk = inner ^ ((row & 7) << 4);
            GLD16((const char*)A + ((size_t)(m0 + row) * K + kt) * 2 + srk, (char*)lA + o);
        }
        #pragma unroll
        for (int c = 0; c < 2; ++c) {   // stage B tile 8KB
            int o = (tid + c * 256) * 16;
            int row = o >> 7, inner = o & 127;
            int srk = inner ^ ((row & 7) << 4);
            GLD16((const char*)BT + ((size_t)(n0 + row) * K + kt) * 2 + srk, (char*)lB + o);
        }
        __syncthreads();
        #pragma unroll
        for (int kc = 0; kc < 2; ++kc) {
            const int kb = kc * 64 + ((lane >> 4) << 4);
            short8 bf[2];
            #pragma unroll
            for (int nf = 0; nf < 2; ++nf) {
                int nn = wn + nf * 16 + (lane & 15);
                bf[nf] = *(const short8*)((const char*)lB + nn * 128 + (kb ^ ((nn & 7) << 4)));
            }
            #pragma unroll
            for (int mf = 0; mf < 4; ++mf) {
                int rr = wm + mf * 16 + (lane & 15);
                short8 af = *(const short8*)((const char*)lA + rr * 128 + (kb ^ ((rr & 7) << 4)));
                acc[mf][0] = __builtin_amdgcn_mfma_f32_16x16x32_bf16(af, bf[0], acc[mf][0], 0, 0, 0);
                acc[mf][1] = __builtin_amdgcn_mfma_f32_16x16x32_bf16(af, bf[1], acc[mf][1], 0, 0, 0);
            }
        }
    }
    #pragma unroll
    for (int mf = 0; mf < 4; ++mf)
        #pragma unroll
        for (int nf = 0; nf < 2; ++nf)
            #pragma unroll
            for (int r = 0; r < 4; ++r) {
                int row = m0 + wm + mf * 16 + ((lane >> 4) << 2) + r;
                int col = n0 + wn + nf * 16 + (lane & 15);
                float v = acc[mf][nf][r] + bias[col];
                if (EPI == 2) v += extra[col];
                if (EPI == 3 || EPI == 4) v += extra[(size_t)row * N + col];
                if (EPI == 1) v = fmaxf(v, 0.f);
                if (EPI == 4) {
                    if (isnan(v)) v = 0.f;
                    else if (isinf(v)) v = v > 0.f ? 3.402823466e38f : -3.402823466e38f;
                }
                if (EPI == 0 || EPI == 1)
                    ((unsigned short*)outp)[(size_t)row * N + col] = f2b(v);
                else
                    ((float*)outp)[(size_t)row * N + col] = v;
            }
}

// ---------------- LayerNorm (f32 in, bf16 out), one wave per 256-row ----------------
__global__ __launch_bounds__(256, 2)
void k_ln(const float* x, const float* g, const float* b, unsigned short* out)
{
    int row = blockIdx.x * 4 + (threadIdx.x >> 6);
    int lane = threadIdx.x & 63;
    const float* xr = x + (size_t)row * 256;
    float4 v = ((const float4*)xr)[lane];
    float s = v.x + v.y + v.z + v.w;
    #pragma unroll
    for (int t = 32; t >= 1; t >>= 1) s += __shfl_xor(s, t, 64);
    float mean = s * (1.f / 256.f);
    float d0 = v.x - mean, d1 = v.y - mean, d2 = v.z - mean, d3 = v.w - mean;
    float q = d0 * d0 + d1 * d1 + d2 * d2 + d3 * d3;
    #pragma unroll
    for (int t = 32; t >= 1; t >>= 1) q += __shfl_xor(q, t, 64);
    float inv = 1.0f / sqrtf(q * (1.f / 256.f) + 1e-5f);
    int c = lane * 4;
    unsigned long long p =
          (unsigned long long)f2b(d0 * inv * g[c] + b[c])
        | ((unsigned long long)f2b(d1 * inv * g[c + 1] + b[c + 1]) << 16)
        | ((unsigned long long)f2b(d2 * inv * g[c + 2] + b[c + 2]) << 32)
        | ((unsigned long long)f2b(d3 * inv * g[c + 3] + b[c + 3]) << 48);
    ((unsigned long long*)(out + (size_t)row * 256))[lane] = p;
}

// ---------------- k_cook: gather + pos-enc -> cooked nx in GLOBAL (swizzled image) ----
// One thread = one (row, 64-col chunk). Half = 8192 queries = 131072 rows = 524288 items.
// Pure streaming/gather: no LDS, no barriers, no MFMA -> high occupancy hides latency.
__global__ __launch_bounds__(256, 6)
void k_cook(const unsigned short* srcp, const int* inds, const float* s_pts, const float* q_pts,
            const float* W_pos, const float* bp2, unsigned short* gnx, float* gdist, int qoff)
{
    int item = blockIdx.x * 256 + threadIdx.x;   // 0 .. 524287
    int r = item >> 2, sub = item & 3;           // half-local row, 64-col chunk
    int qi = qoff + (r >> 4);
    int bb = qi >> 12;
    int k = r & 15;
    int raw = inds[((size_t)qi << 4) + k];
    int idx = raw % (NS + 1); if (idx < 0) idx += NS + 1;
    bool shadow = (idx == NS);
    const unsigned short* srow = srcp + ((size_t)bb * NS + (shadow ? 0 : idx)) * 256 + sub * 64;

    float px = q_pts[(size_t)qi * 3], py = q_pts[(size_t)qi * 3 + 1], pz = q_pts[(size_t)qi * 3 + 2];
    float sx, sy, sz;
    if (shadow) { sx = sy = sz = 1e6f; }
    else { const float* sp = s_pts + ((size_t)bb * NS + idx) * 3; sx = sp[0]; sy = sp[1]; sz = sp[2]; }
    float tx = (sx - px) * 0.25f, ty = (sy - py) * 0.25f, tz = (sz - pz) * 0.25f;
    if (sub == 0) gdist[r] = tx * tx + ty * ty + tz * tz;   // >1 <=> dist>RADIUS

    const int c0 = sub * 64;
    #pragma unroll 1
    for (int half = 0; half < 2; ++half) {                  // 2x4 chunks: cap live sv regs
        short8 sv[4];
        #pragma unroll
        for (int j = 0; j < 4; ++j) sv[j] = *(const short8*)(srow + half * 32 + j * 8);
        #pragma unroll
        for (int cc = half * 32; cc < half * 32 + 32; cc += 8) {
            float f[8];
            #pragma unroll
            for (int j = 0; j < 8; ++j) {
                int c = c0 + cc + j;
                float pe;
                if (c == 0) pe = tx;
                else if (c == 1) pe = ty;
                else if (c == 2) pe = tz;
                else {
                    int jj = c - 3;
                    float rev = fmaf(tx, W_pos[jj], fmaf(ty, W_pos[253 + jj], fmaf(tz, W_pos[506 + jj], bp2[jj])));
                    rev -= floorf(rev);
                    pe = __builtin_amdgcn_cosf(rev);
                }
                f[j] = (shadow ? 0.f : b2f((unsigned short)sv[(cc / 8) & 3][j])) + pe;
            }
            unsigned int w0, w1, w2, w3;
            asm("v_cvt_pk_bf16_f32 %0, %1, %2" : "=v"(w0) : "v"(f[0]), "v"(f[1]));
            asm("v_cvt_pk_bf16_f32 %0, %1, %2" : "=v"(w1) : "v"(f[2]), "v"(f[3]));
            asm("v_cvt_pk_bf16_f32 %0, %1, %2" : "=v"(w2) : "v"(f[4]), "v"(f[5]));
            asm("v_cvt_pk_bf16_f32 %0, %1, %2" : "=v"(w3) : "v"(f[6]), "v"(f[7]));
            int byte = (c0 + cc) * 2;
            *(uint4*)((char*)gnx + (size_t)r * 512 + (byte ^ ((r & 7) << 4))) = make_uint4(w0, w1, w2, w3);
        }
    }
}

// ---------------- k_attn2: single-pass K/V projection + in-register softmax/ctx ------
// block = 256 thr (4 waves) = 4 queries (64 rows). nx staged linearly (swizzle baked).
// ONE kt-loop computes kk AND vv accumulators (32 MFMA/kt covers weight-load latency).
// Softmax p-values share the (rr,lg) k-distribution with acc_v -> ctx fully in regs.
__global__ __launch_bounds__(256, 4)
void k_attn2(const unsigned short* gnx, const float* gdist, const unsigned short* qb,
             const unsigned short* wTkv, const float* bv, unsigned short* ctx, int qoff)
{
    __shared__ alignas(1024) unsigned short nxL[64 * 256];  // 32 KB swizzled image
    __shared__ alignas(16) float dist_lds[64];
    const int tid = threadIdx.x, wave = tid >> 6, lane = tid & 63;
    const int l15 = lane & 15, lg = lane >> 4;
    const int qlocal = blockIdx.x * 4;          // half-local first query
    const int qbase = qoff + qlocal;            // global first query
    const int wn = wave * 64;                   // wave's 64 cols = heads 4w..4w+3

    // stage 32 KB of cooked nx (linear copy: swizzle travels intact)
    {
        const char* src = (const char*)gnx + (size_t)qlocal * 16 * 512;
        #pragma unroll
        for (int c = 0; c < 8; ++c) {
            int o = (tid + c * 256) * 16;
            GLD16(src + o, (char*)nxL + o);
        }
        if (tid < 64) dist_lds[tid] = gdist[qlocal * 16 + tid];
    }

    // preload (independent of LDS, issued before the barrier):
    float qv[4][4], bvv[4];
    #pragma unroll
    for (int mf = 0; mf < 4; ++mf)
        #pragma unroll
        for (int nf = 0; nf < 4; ++nf)
            qv[mf][nf] = b2f(qb[(size_t)(qbase + mf) * 256 + (wave * 4 + nf) * 16 + l15]) * 0.25f;
    #pragma unroll
    for (int nf = 0; nf < 4; ++nf) bvv[nf] = bv[(wave * 4 + nf) * 16 + l15];
    short8 wkc[4], wvc[4];
    #pragma unroll
    for (int nf = 0; nf < 4; ++nf) {
        const char* bp = (const char*)wTkv + (size_t)(wn + nf * 16 + l15) * 512 + (lg << 4);
        wkc[nf] = *(const short8*)bp;
        wvc[nf] = *(const short8*)(bp + 256 * 512);
    }

    __syncthreads();

    // ---- single-pass: kk and vv accumulate together; depth-1 weight prefetch ----
    floatx4 ak[4][4] = {}, av[4][4] = {};
    #pragma unroll
    for (int kt = 0; kt < 8; ++kt) {
        short8 wkn[4], wvn[4];
        if (kt < 7) {
            #pragma unroll
            for (int nf = 0; nf < 4; ++nf) {
                const char* bp = (const char*)wTkv + (size_t)(wn + nf * 16 + l15) * 512
                               + (kt + 1) * 64 + (lg << 4);
                wkn[nf] = *(const short8*)bp;
                wvn[nf] = *(const short8*)(bp + 256 * 512);
            }
        }
        #pragma unroll
        for (int mf = 0; mf < 4; ++mf) {
            int rr = mf * 16 + l15;
            short8 af = *(const short8*)((const char*)nxL + rr * 512
                         + ((kt * 64 + (lg << 4)) ^ ((rr & 7) << 4)));
            #pragma unroll
            for (int nf = 0; nf < 4; ++nf) {
                ak[mf][nf] = __builtin_amdgcn_mfma_f32_16x16x32_bf16(af, wkc[nf], ak[mf][nf], 0, 0, 0);
                av[mf][nf] = __builtin_amdgcn_mfma_f32_16x16x32_bf16(af, wvc[nf], av[mf][nf], 0, 0, 0);
            }
        }
        #pragma unroll
        for (int nf = 0; nf < 4; ++nf) { wkc[nf] = wkn[nf]; wvc[nf] = wvn[nf]; }
    }

    // ---- fused softmax + ctx (all in registers) ----
    // ak[mf][nf][rr] = kk[k = lg*4+rr][h*16 + dd], h = wave*4+nf, dd = l15. Same for av.
    #pragma unroll
    for (int mf = 0; mf < 4; ++mf) {
        float4 d4 = *(const float4*)&dist_lds[mf * 16 + lg * 4];
        float dd4[4] = {d4.x, d4.y, d4.z, d4.w};
        #pragma unroll
        for (int nf = 0; nf < 4; ++nf) {
            float s[4];
            #pragma unroll
            for (int rr = 0; rr < 4; ++rr) s[rr] = ak[mf][nf][rr] * qv[mf][nf];
            #pragma unroll
            for (int t = 1; t <= 8; t <<= 1)
                #pragma unroll
                for (int rr = 0; rr < 4; ++rr) s[rr] += __shfl_xor(s[rr], t);
            #pragma unroll
            for (int rr = 0; rr < 4; ++rr)
                s[rr] = (dd4[rr] > 1.0f) ? -1e9f : s[rr];
            float m = fmaxf(fmaxf(s[0], s[1]), fmaxf(s[2], s[3]));
            m = fmaxf(m, __shfl_xor(m, 16));
            m = fmaxf(m, __shfl_xor(m, 32));
            float p[4], su = 0.f;
            #pragma unroll
            for (int rr = 0; rr < 4; ++rr) { p[rr] = __expf(s[rr] - m); su += p[rr]; }
            su += __shfl_xor(su, 16);
            su += __shfl_xor(su, 32);
            float inv = __builtin_amdgcn_rcpf(su);
            // ctx: p distribution over (lg,rr) matches av's k distribution exactly
            float o = p[0] * av[mf][nf][0];
            o = fmaf(p[1], av[mf][nf][1], o);
            o = fmaf(p[2], av[mf][nf][2], o);
            o = fmaf(p[3], av[mf][nf][3], o);
            o += __shfl_xor(o, 16);
            o += __shfl_xor(o, 32);
            o = fmaf(o, inv, bvv[nf]);
            if (lane < 16)
                ctx[(size_t)(qbase + mf) * 256 + (wave * 4 + nf) * 16 + lane] = f2b(o);
        }
    }
}

// ---------------- host launcher ----------------
extern "C" void kernel_launch(void* const* d_in, const int* in_sizes, int n_in,
                              void* d_out, int out_size, void* d_ws, size_t ws_size,
                              hipStream_t stream)
{
    const float* q_pts   = (const float*)d_in[0];
    const float* s_pts   = (const float*)d_in[1];
    const float* src_f   = (const float*)d_in[2];
    const float* query_f = (const float*)d_in[3];
    const float* W_proj  = (const float*)d_in[4];
    const float* b_proj  = (const float*)d_in[5];
    const float* W_pos   = (const float*)d_in[6];
    const float* b_pos   = (const float*)d_in[7];
    const float* ln1_g   = (const float*)d_in[8];
    const float* ln1_b   = (const float*)d_in[9];
    const float* sa_Wv   = (const float*)d_in[10];
    const float* sa_bv   = (const float*)d_in[11];
    const float* sa_Wo   = (const float*)d_in[12];
    const float* sa_bo   = (const float*)d_in[13];
    const float* ln2_g   = (const float*)d_in[14];
    const float* ln2_b   = (const float*)d_in[15];
    const float* ca_Wq   = (const float*)d_in[16];
    const float* ca_bq   = (const float*)d_in[17];
    const float* ca_Wk   = (const float*)d_in[18];
    /* ca_bk = d_in[19] unused: softmax shift-invariant */
    const float* ca_Wv   = (const float*)d_in[20];
    const float* ca_bv   = (const float*)d_in[21];
    const float* ca_Wo   = (const float*)d_in[22];
    const float* ca_bo   = (const float*)d_in[23];
    const float* ln3_g   = (const float*)d_in[24];
    const float* ln3_b   = (const float*)d_in[25];
    const float* W1      = (const float*)d_in[26];
    const float* b1      = (const float*)d_in[27];
    const float* W2      = (const float*)d_in[28];
    const float* b2      = (const float*)d_in[29];
    const int*   inds    = (const int*)d_in[30];

    char* ws = (char*)d_ws;
    size_t off = 0;
    auto alloc = [&](size_t bytes) { char* p = ws + off; off += (bytes + 1023) & ~(size_t)1023; return p; };

    unsigned short* wTproj = (unsigned short*)alloc(256 * 128 * 2);
    unsigned short* wTsaWv = (unsigned short*)alloc(256 * 256 * 2);
    unsigned short* wTsaWo = (unsigned short*)alloc(256 * 256 * 2);
    unsigned short* wTcaWq = (unsigned short*)alloc(256 * 256 * 2);
    unsigned short* wTkv   = (unsigned short*)alloc(512 * 256 * 2);
    unsigned short* wTcaWo = (unsigned short*)alloc(256 * 256 * 2);
    unsigned short* wTW1   = (unsigned short*)alloc(256 * 256 * 2);
    unsigned short* wTW2   = (unsigned short*)alloc(256 * 256 * 2);
    float*          penc0  = (float*)alloc(256 * 4);
    float*          bp2    = (float*)alloc(256 * 4);
    unsigned short* srcb   = (unsigned short*)alloc((size_t)NROW_S * 128 * 2);
    unsigned short* qfb    = (unsigned short*)alloc((size_t)NROW_Q * 128 * 2);
    unsigned short* srcp   = (unsigned short*)alloc((size_t)NROW_S * 256 * 2);
    float*          qx     = (float*)alloc((size_t)NROW_Q * 256 * 4);
    unsigned short* hbuf   = (unsigned short*)alloc((size_t)NROW_Q * 256 * 2);
    unsigned short* tbuf   = (unsigned short*)alloc((size_t)NROW_Q * 256 * 2);
    float*          xbuf   = (float*)alloc((size_t)NROW_Q * 256 * 4);
    unsigned short* qbuf   = (unsigned short*)alloc((size_t)NROW_Q * 256 * 2);
    unsigned short* ctxbuf = (unsigned short*)alloc((size_t)NROW_Q * 256 * 2);
    float*          x2buf  = (float*)alloc((size_t)NROW_Q * 256 * 4);
    unsigned short* gnx    = (unsigned short*)alloc((size_t)NQH * 16 * 256 * 2);   // 67 MB (reused per half)
    float*          gdist  = (float*)alloc((size_t)NQH * 16 * 4);

    dim3 bl16(16, 16);
    k_prep<<<dim3(16, 16, 10), bl16, 0, stream>>>(
        W_proj, sa_Wv, sa_Wo, ca_Wq, ca_Wk, ca_Wv, ca_Wo, W1, W2, b_pos,
        wTproj, wTsaWv, wTsaWo, wTcaWq, wTkv, wTcaWo, wTW1, wTW2, penc0);
    k_scale<<<1, 256, 0, stream>>>(b_pos, bp2);

    k_cvt<<<1024, 256, 0, stream>>>(src_f, srcb, NROW_S * 128 / 4);
    k_cvt<<<1024, 256, 0, stream>>>(query_f, qfb, NROW_Q * 128 / 4);

    // src_p = src @ W_proj + b_proj  (bf16)
    k_gemm<0><<<dim3(512, 4), 256, 0, stream>>>(srcb, wTproj, b_proj, nullptr, srcp, NROW_S, 256, 128);
    // query_x = query @ W_proj + b_proj + pos_enc(0)  (f32 master)
    k_gemm<2><<<dim3(128, 4), 256, 0, stream>>>(qfb, wTproj, b_proj, penc0, qx, NROW_Q, 256, 128);

    // self-attention block (seq len 1): x = qx + (ln1(qx)@saWv+bv)@saWo+bo
    k_ln<<<4096, 256, 0, stream>>>(qx, ln1_g, ln1_b, hbuf);
    k_gemm<0><<<dim3(128, 4), 256, 0, stream>>>(hbuf, wTsaWv, sa_bv, nullptr, tbuf, NROW_Q, 256, 256);
    k_gemm<3><<<dim3(128, 4), 256, 0, stream>>>(tbuf, wTsaWo, sa_bo, qx, xbuf, NROW_Q, 256, 256);

    // cross-attention (de-fused: cook -> attn2, two halves reusing gnx)
    k_ln<<<4096, 256, 0, stream>>>(xbuf, ln2_g, ln2_b, hbuf);
    k_gemm<0><<<dim3(128, 4), 256, 0, stream>>>(hbuf, wTcaWq, ca_bq, nullptr, qbuf, NROW_Q, 256, 256);
    for (int h = 0; h < 2; ++h) {
        int qoff = h * NQH;
        k_cook<<<2048, 256, 0, stream>>>(srcp, inds, s_pts, q_pts, W_pos, bp2, gnx, gdist, qoff);
        k_attn2<<<2048, 256, 0, stream>>>(gnx, gdist, qbuf, wTkv, ca_bv, ctxbuf, qoff);
    }
    k_gemm<3><<<dim3(128, 4), 256, 0, stream>>>(ctxbuf, wTcaWo, ca_bo, xbuf, x2buf, NROW_Q, 256, 256);

    // feed-forward + nan_to_num -> d_out (f32)
    k_ln<<<4096, 256, 0, stream>>>(x2buf, ln3_g, ln3_b, hbuf);
    k_gemm<1><<<dim3(128, 4), 256, 0, stream>>>(hbuf, wTW1, b1, nullptr, tbuf, NROW_Q, 256, 256);
    k_gemm<4><<<dim3(128, 4), 256, 0, stream>>>(tbuf, wTW2, b2, x2buf, d_out, NROW_Q, 256, 256);

    (void)in_sizes; (void)n_in; (void)out_size; (void)ws_size;
}

// Round 9
// 506.503 us; speedup vs baseline: 2.2975x; 2.2975x over previous
//
#include <hip/hip_runtime.h>
#include <hip/hip_bf16.h>
#include <math.h>
#include <stdint.h>

// ---------------- types & helpers ----------------
typedef __attribute__((ext_vector_type(8))) short short8;   // 8 x bf16 (MFMA A/B frag)
typedef __attribute__((ext_vector_type(4))) float floatx4;  // MFMA C/D frag

#define DEVI __device__ __forceinline__

DEVI float b2f(unsigned short u) {
    union { unsigned int i; float f; } v; v.i = ((unsigned int)u) << 16; return v.f;
}
DEVI unsigned short f2b(float f) {   // RNE f32 -> bf16
    unsigned int x = __float_as_uint(f);
    unsigned int r = (x + 0x7fffu + ((x >> 16) & 1u)) >> 16;
    return (unsigned short)r;
}

// global -> LDS direct (16B per lane). LDS dest must be wave-uniform base + lane*16.
#define GLD16(gp, lp)                                                            \
    __builtin_amdgcn_global_load_lds(                                            \
        (__attribute__((address_space(1))) unsigned int*)(gp),                   \
        (__attribute__((address_space(3))) unsigned int*)(lp), 16, 0, 0)

static constexpr int NQ = 4096, NS = 16384;
static constexpr int NROW_Q = 4 * NQ;   // 16384 query rows
static constexpr int NROW_S = 4 * NS;   // 65536 source rows
static constexpr float INV2PI = 0.15915494309189535f;

// ---------------- prep: transpose weights to bf16 [N][K], penc0 ----------------
__global__ void k_prep(const float* Wproj, const float* saWv, const float* saWo,
                       const float* caWq, const float* caWk, const float* caWv,
                       const float* caWo, const float* W1, const float* W2,
                       const float* b_pos,
                       unsigned short* wTproj, unsigned short* wTsaWv, unsigned short* wTsaWo,
                       unsigned short* wTcaWq, unsigned short* wTkv, unsigned short* wTcaWo,
                       unsigned short* wTW1, unsigned short* wTW2, float* penc0)
{
    int z = blockIdx.z;
    if (z == 9) {   // penc0[c] = pos_enc(0): [0,0,0, cos(b_pos)]
        if (blockIdx.x == 0 && blockIdx.y == 0) {
            int c = threadIdx.y * 16 + threadIdx.x;
            float v = 0.f;
            if (c >= 3) {
                float rev = b_pos[c - 3] * INV2PI;
                rev -= floorf(rev);
                v = __builtin_amdgcn_cosf(rev);
            }
            penc0[c] = v;
        }
        return;
    }
    int n = blockIdx.x * 16 + threadIdx.x;   // output row (orig col)
    int k = blockIdx.y * 16 + threadIdx.y;   // output col (orig row)
    const float* src; unsigned short* dst; int K = 256;
    switch (z) {
        case 0: src = Wproj; dst = wTproj; K = 128; break;
        case 1: src = saWv;  dst = wTsaWv; break;
        case 2: src = saWo;  dst = wTsaWo; break;
        case 3: src = caWq;  dst = wTcaWq; break;
        case 4: src = caWk;  dst = wTkv;   break;
        case 5: src = caWv;  dst = wTkv + 256 * 256; break;
        case 6: src = caWo;  dst = wTcaWo; break;
        case 7: src = W1;    dst = wTW1;   break;
        default: src = W2;   dst = wTW2;   break;
    }
    if (k < K) dst[(size_t)n * K + k] = f2b(src[(size_t)k * 256 + n]);
}

// scale b_pos by 1/2pi (W_pos must stay UNSCALED: revolutions = x.W + b/2pi)
__global__ void k_scale(const float* b_pos, float* bp2)
{
    int i = blockIdx.x * blockDim.x + threadIdx.x;
    if (i < 253) bp2[i] = b_pos[i] * INV2PI;
}

// ---------------- f32 -> bf16 convert ----------------
__global__ void k_cvt(const float* in, unsigned short* out, int n4)
{
    int i = blockIdx.x * blockDim.x + threadIdx.x;
    int stride = gridDim.x * blockDim.x;
    for (; i < n4; i += stride) {
        float4 v = ((const float4*)in)[i];
        unsigned long long p =
              (unsigned long long)f2b(v.x)
            | ((unsigned long long)f2b(v.y) << 16)
            | ((unsigned long long)f2b(v.z) << 32)
            | ((unsigned long long)f2b(v.w) << 48);
        ((unsigned long long*)out)[i] = p;
    }
}

// ---------------- MFMA GEMM: out[M][N] = A[M][K](bf16) @ BT[N][K]^T + epilogue ----------------
// EPI: 0 = bf16 out, +bias            1 = bf16 out, +bias, relu
//      2 = f32 out, +bias +extra[col] 3 = f32 out, +bias +extra[row,col]
//      4 = f32 out, +bias +extra[row,col], nan_to_num
template<int EPI>
__global__ __launch_bounds__(256, 2)
void k_gemm(const unsigned short* A, const unsigned short* BT, const float* bias,
            const float* extra, void* outp, int M, int N, int K)
{
    __shared__ alignas(16) unsigned short lA[128 * 64];  // [128 rows][64 k], swizzled
    __shared__ alignas(16) unsigned short lB[64 * 64];   // [64 rows][64 k], swizzled
    const int tid = threadIdx.x;
    const int wave = tid >> 6, lane = tid & 63;
    const int m0 = blockIdx.x * 128, n0 = blockIdx.y * 64;
    const int wm = (wave >> 1) * 64, wn = (wave & 1) * 32;
    floatx4 acc[4][2] = {};

    for (int kt = 0; kt < K; kt += 64) {
        __syncthreads();
        #pragma unroll
        for (int c = 0; c < 4; ++c) {   // stage A tile 16KB
            int o = (tid + c * 256) * 16;
            int row = o >> 7, inner = o & 127;
            int srk = inner ^ ((row & 7) << 4);
            GLD16((const char*)A + ((size_t)(m0 + row) * K + kt) * 2 + srk, (char*)lA + o);
        }
        #pragma unroll
        for (int c = 0; c < 2; ++c) {   // stage B tile 8KB
            int o = (tid + c * 256) * 16;
            int row = o >> 7, inner = o & 127;
            int srk = inner ^ ((row & 7) << 4);
            GLD16((const char*)BT + ((size_t)(n0 + row) * K + kt) * 2 + srk, (char*)lB + o);
        }
        __syncthreads();
        #pragma unroll
        for (int kc = 0; kc < 2; ++kc) {
            const int kb = kc * 64 + ((lane >> 4) << 4);
            short8 bf[2];
            #pragma unroll
            for (int nf = 0; nf < 2; ++nf) {
                int nn = wn + nf * 16 + (lane & 15);
                bf[nf] = *(const short8*)((const char*)lB + nn * 128 + (kb ^ ((nn & 7) << 4)));
            }
            #pragma unroll
            for (int mf = 0; mf < 4; ++mf) {
                int rr = wm + mf * 16 + (lane & 15);
                short8 af = *(const short8*)((const char*)lA + rr * 128 + (kb ^ ((rr & 7) << 4)));
                acc[mf][0] = __builtin_amdgcn_mfma_f32_16x16x32_bf16(af, bf[0], acc[mf][0], 0, 0, 0);
                acc[mf][1] = __builtin_amdgcn_mfma_f32_16x16x32_bf16(af, bf[1], acc[mf][1], 0, 0, 0);
            }
        }
    }
    #pragma unroll
    for (int mf = 0; mf < 4; ++mf)
        #pragma unroll
        for (int nf = 0; nf < 2; ++nf)
            #pragma unroll
            for (int r = 0; r < 4; ++r) {
                int row = m0 + wm + mf * 16 + ((lane >> 4) << 2) + r;
                int col = n0 + wn + nf * 16 + (lane & 15);
                float v = acc[mf][nf][r] + bias[col];
                if (EPI == 2) v += extra[col];
                if (EPI == 3 || EPI == 4) v += extra[(size_t)row * N + col];
                if (EPI == 1) v = fmaxf(v, 0.f);
                if (EPI == 4) {
                    if (isnan(v)) v = 0.f;
                    else if (isinf(v)) v = v > 0.f ? 3.402823466e38f : -3.402823466e38f;
                }
                if (EPI == 0 || EPI == 1)
                    ((unsigned short*)outp)[(size_t)row * N + col] = f2b(v);
                else
                    ((float*)outp)[(size_t)row * N + col] = v;
            }
}

// ---------------- LayerNorm (f32 in, bf16 out), one wave per 256-row ----------------
__global__ __launch_bounds__(256, 2)
void k_ln(const float* x, const float* g, const float* b, unsigned short* out)
{
    int row = blockIdx.x * 4 + (threadIdx.x >> 6);
    int lane = threadIdx.x & 63;
    const float* xr = x + (size_t)row * 256;
    float4 v = ((const float4*)xr)[lane];
    float s = v.x + v.y + v.z + v.w;
    #pragma unroll
    for (int t = 32; t >= 1; t >>= 1) s += __shfl_xor(s, t, 64);
    float mean = s * (1.f / 256.f);
    float d0 = v.x - mean, d1 = v.y - mean, d2 = v.z - mean, d3 = v.w - mean;
    float q = d0 * d0 + d1 * d1 + d2 * d2 + d3 * d3;
    #pragma unroll
    for (int t = 32; t >= 1; t >>= 1) q += __shfl_xor(q, t, 64);
    float inv = 1.0f / sqrtf(q * (1.f / 256.f) + 1e-5f);
    int c = lane * 4;
    unsigned long long p =
          (unsigned long long)f2b(d0 * inv * g[c] + b[c])
        | ((unsigned long long)f2b(d1 * inv * g[c + 1] + b[c + 1]) << 16)
        | ((unsigned long long)f2b(d2 * inv * g[c + 2] + b[c + 2]) << 32)
        | ((unsigned long long)f2b(d3 * inv * g[c + 3] + b[c + 3]) << 48);
    ((unsigned long long*)(out + (size_t)row * 256))[lane] = p;
}

// ---------------- k_attn3: fused gather+cook+projection+softmax+ctx (single buffer) ----
// block = 256 thr (4 waves) = 4 queries (64 neighbor rows). 37.4 KB LDS.
// Phase A: t-vecs -> LDS; raw gather via 8xGLD16/thread (pre-swizzled global source,
//          zero VGPRs held); preload qv/bv. __syncthreads (vmcnt drain wanted).
// Phase B: in-place LDS RMW cook (add pos-enc, zero shadow rows). __syncthreads.
// Phase C: proven r7 compute: P2 kk (acc[4][4]) -> P3 softmax -> P4 vv -> ctx.
__global__ __launch_bounds__(256, 3)
void k_attn3(const unsigned short* srcp, const unsigned short* qb, const int* inds,
             const float* s_pts, const float* q_pts, const float* W_pos, const float* bp2,
             const unsigned short* wTkv, const float* bv, unsigned short* ctx)
{
    __shared__ alignas(1024) unsigned short nx[64 * 256];   // 32 KB swizzled (raw->cooked)
    __shared__ alignas(16) float4 t_lds[64];                // {tx,ty,tz, +-dist2 (neg=shadow)}
    __shared__ alignas(16) float att_lds[4 * 16 * 16];      // 4 KB [q][h][k]
    const int tid = threadIdx.x, wave = tid >> 6, lane = tid & 63;
    const int l15 = lane & 15, lg = lane >> 4;
    const int l31 = lane & 31, lh = lane >> 5;
    const int qbase = blockIdx.x * 4;
    const int wn = wave * 64;   // wave's 64 cols = heads 4w..4w+3

    // ---- Phase A: t-vecs + raw gather ----
    if ((tid & 3) == 0) {                     // thread 4r computes t/dist for row r
        int rr = tid >> 2;
        int qi = qbase + (rr >> 4);
        int bb = qi >> 12;
        int raw = inds[((size_t)qi << 4) + (rr & 15)];
        int idx = raw % (NS + 1); if (idx < 0) idx += NS + 1;
        bool sh = (idx == NS);
        float px = q_pts[(size_t)qi * 3], py = q_pts[(size_t)qi * 3 + 1], pz = q_pts[(size_t)qi * 3 + 2];
        float sx, sy, sz;
        if (sh) { sx = sy = sz = 1e6f; }
        else { const float* sp = s_pts + ((size_t)bb * NS + idx) * 3; sx = sp[0]; sy = sp[1]; sz = sp[2]; }
        float tx = (sx - px) * 0.25f, ty = (sy - py) * 0.25f, tz = (sz - pz) * 0.25f;
        float d2 = tx * tx + ty * ty + tz * tz;
        t_lds[rr] = make_float4(tx, ty, tz, sh ? -d2 : d2);
    }
    #pragma unroll
    for (int c = 0; c < 8; ++c) {             // 8 x GLD16 per thread = 32KB/block
        int row = wave * 16 + c * 2 + lh;
        int qi = qbase + (row >> 4);
        int bb = qi >> 12;
        int raw = inds[((size_t)qi << 4) + (row & 15)];
        int idx = raw % (NS + 1); if (idx < 0) idx += NS + 1;
        int srow = (idx == NS) ? 0 : idx;     // shadow rows zeroed in cook
        const char* gp = (const char*)(srcp + ((size_t)bb * NS + srow) * 256)
                       + ((l31 * 16) ^ ((row & 7) << 4));   // pre-swizzled source
        char* lp = (char*)nx + wave * 8192 + c * 1024 + lane * 16;
        GLD16(gp, lp);
    }
    // preload q fragments & bias (independent of LDS)
    float qv[4][4], bvv[4];
    #pragma unroll
    for (int mf = 0; mf < 4; ++mf)
        #pragma unroll
        for (int nf = 0; nf < 4; ++nf)
            qv[mf][nf] = b2f(qb[(size_t)(qbase + mf) * 256 + (wave * 4 + nf) * 16 + l15]) * 0.25f;
    #pragma unroll
    for (int nf = 0; nf < 4; ++nf) bvv[nf] = bv[(wave * 4 + nf) * 16 + l15];

    __syncthreads();   // raw nx + t_lds ready (vmcnt+lgkm drained)

    // ---- Phase B: cook in place ----
    #pragma unroll
    for (int c = 0; c < 8; ++c) {
        int row = wave * 16 + c * 2 + lh;
        char* slot = (char*)nx + wave * 8192 + c * 1024 + lane * 16;
        uint4 rawv = *(uint4*)slot;
        float4 t4 = t_lds[row];
        bool sh = (t4.w < 0.f);
        int cc = (((l31 * 16) ^ ((row & 7) << 4)) >> 1);   // logical col (8-aligned)
        float f[8];
        #pragma unroll
        for (int j = 0; j < 8; ++j) {
            int c_ = cc + j;
            float pe;
            if (c_ == 0) pe = t4.x;
            else if (c_ == 1) pe = t4.y;
            else if (c_ == 2) pe = t4.z;
            else {
                int jj = c_ - 3;
                float rev = fmaf(t4.x, W_pos[jj],
                            fmaf(t4.y, W_pos[253 + jj],
                            fmaf(t4.z, W_pos[506 + jj], bp2[jj])));
                rev -= floorf(rev);
                pe = __builtin_amdgcn_cosf(rev);
            }
            unsigned int uj = ((const unsigned int*)&rawv)[j >> 1];
            unsigned short us = (j & 1) ? (unsigned short)(uj >> 16)
                                        : (unsigned short)(uj & 0xffffu);
            f[j] = (sh ? 0.f : b2f(us)) + pe;
        }
        unsigned int w0, w1, w2, w3;
        asm("v_cvt_pk_bf16_f32 %0, %1, %2" : "=v"(w0) : "v"(f[0]), "v"(f[1]));
        asm("v_cvt_pk_bf16_f32 %0, %1, %2" : "=v"(w1) : "v"(f[2]), "v"(f[3]));
        asm("v_cvt_pk_bf16_f32 %0, %1, %2" : "=v"(w2) : "v"(f[4]), "v"(f[5]));
        asm("v_cvt_pk_bf16_f32 %0, %1, %2" : "=v"(w3) : "v"(f[6]), "v"(f[7]));
        *(uint4*)slot = make_uint4(w0, w1, w2, w3);
    }
    __syncthreads();   // cooked nx visible

    // ---- Phase C: P2 kk = nx @ Wk (acc[4][4] only — proven no-spill config) ----
    floatx4 acc[4][4];
    #pragma unroll
    for (int mf = 0; mf < 4; ++mf)
        #pragma unroll
        for (int nf = 0; nf < 4; ++nf) acc[mf][nf] = floatx4{0.f, 0.f, 0.f, 0.f};

    #pragma unroll 2
    for (int kt = 0; kt < 8; ++kt) {
        const int kb = kt * 64 + (lg << 4);
        short8 bfr[4];
        #pragma unroll
        for (int nf = 0; nf < 4; ++nf) {
            int nn = wn + nf * 16 + l15;
            bfr[nf] = *(const short8*)((const char*)wTkv + (size_t)nn * 512 + kt * 64 + (lg << 4));
        }
        #pragma unroll
        for (int mf = 0; mf < 4; ++mf) {
            int rr = mf * 16 + l15;
            short8 af = *(const short8*)((const char*)nx + rr * 512 + (kb ^ ((rr & 7) << 4)));
            #pragma unroll
            for (int nf = 0; nf < 4; ++nf)
                acc[mf][nf] = __builtin_amdgcn_mfma_f32_16x16x32_bf16(af, bfr[nf], acc[mf][nf], 0, 0, 0);
        }
    }

    // ---- P3: scores + softmax (in-register) ----
    // acc[mf][nf][rr] = kk[k = lg*4+rr][h*16+dd], h = wave*4+nf, dd = l15
    {
        #pragma unroll
        for (int mf = 0; mf < 4; ++mf) {
            float dd4[4];
            #pragma unroll
            for (int rr = 0; rr < 4; ++rr) dd4[rr] = t_lds[mf * 16 + lg * 4 + rr].w;
            #pragma unroll
            for (int nf = 0; nf < 4; ++nf) {
                float s[4];
                #pragma unroll
                for (int rr = 0; rr < 4; ++rr) s[rr] = acc[mf][nf][rr] * qv[mf][nf];
                #pragma unroll
                for (int t = 1; t <= 8; t <<= 1)
                    #pragma unroll
                    for (int rr = 0; rr < 4; ++rr) s[rr] += __shfl_xor(s[rr], t);
                #pragma unroll
                for (int rr = 0; rr < 4; ++rr)
                    s[rr] = (fabsf(dd4[rr]) > 1.0f) ? -1e9f : s[rr];
                float m = fmaxf(fmaxf(s[0], s[1]), fmaxf(s[2], s[3]));
                m = fmaxf(m, __shfl_xor(m, 16));
                m = fmaxf(m, __shfl_xor(m, 32));
                float p[4], su = 0.f;
                #pragma unroll
                for (int rr = 0; rr < 4; ++rr) { p[rr] = __expf(s[rr] - m); su += p[rr]; }
                su += __shfl_xor(su, 16);
                su += __shfl_xor(su, 32);
                float inv = __builtin_amdgcn_rcpf(su);
                if (l15 == 0) {
                    float4 a4 = {p[0] * inv, p[1] * inv, p[2] * inv, p[3] * inv};
                    *(float4*)&att_lds[(mf * 16 + wave * 4 + nf) * 16 + lg * 4] = a4;
                }
            }
        }
    }

    // ---- P4: vv = nx @ Wv (reuse acc), then ctx = att . vv ----
    #pragma unroll
    for (int mf = 0; mf < 4; ++mf)
        #pragma unroll
        for (int nf = 0; nf < 4; ++nf) acc[mf][nf] = floatx4{0.f, 0.f, 0.f, 0.f};

    #pragma unroll 2
    for (int kt = 0; kt < 8; ++kt) {
        const int kb = kt * 64 + (lg << 4);
        short8 bfr[4];
        #pragma unroll
        for (int nf = 0; nf < 4; ++nf) {
            int nn = 256 + wn + nf * 16 + l15;      // Wv half of wTkv
            bfr[nf] = *(const short8*)((const char*)wTkv + (size_t)nn * 512 + kt * 64 + (lg << 4));
        }
        #pragma unroll
        for (int mf = 0; mf < 4; ++mf) {
            int rr = mf * 16 + l15;
            short8 af = *(const short8*)((const char*)nx + rr * 512 + (kb ^ ((rr & 7) << 4)));
            #pragma unroll
            for (int nf = 0; nf < 4; ++nf)
                acc[mf][nf] = __builtin_amdgcn_mfma_f32_16x16x32_bf16(af, bfr[nf], acc[mf][nf], 0, 0, 0);
        }
    }

    {
        #pragma unroll
        for (int mf = 0; mf < 4; ++mf)
            #pragma unroll
            for (int nf = 0; nf < 4; ++nf) {
                float4 a4 = *(const float4*)&att_lds[(mf * 16 + wave * 4 + nf) * 16 + lg * 4];
                float o = a4.x * acc[mf][nf][0];
                o = fmaf(a4.y, acc[mf][nf][1], o);
                o = fmaf(a4.z, acc[mf][nf][2], o);
                o = fmaf(a4.w, acc[mf][nf][3], o);
                o += __shfl_xor(o, 16);
                o += __shfl_xor(o, 32);
                o += bvv[nf];
                if (lane < 16)
                    ctx[(size_t)(qbase + mf) * 256 + (wave * 4 + nf) * 16 + lane] = f2b(o);
            }
    }
}

// ---------------- host launcher ----------------
extern "C" void kernel_launch(void* const* d_in, const int* in_sizes, int n_in,
                              void* d_out, int out_size, void* d_ws, size_t ws_size,
                              hipStream_t stream)
{
    const float* q_pts   = (const float*)d_in[0];
    const float* s_pts   = (const float*)d_in[1];
    const float* src_f   = (const float*)d_in[2];
    const float* query_f = (const float*)d_in[3];
    const float* W_proj  = (const float*)d_in[4];
    const float* b_proj  = (const float*)d_in[5];
    const float* W_pos   = (const float*)d_in[6];
    const float* b_pos   = (const float*)d_in[7];
    const float* ln1_g   = (const float*)d_in[8];
    const float* ln1_b   = (const float*)d_in[9];
    const float* sa_Wv   = (const float*)d_in[10];
    const float* sa_bv   = (const float*)d_in[11];
    const float* sa_Wo   = (const float*)d_in[12];
    const float* sa_bo   = (const float*)d_in[13];
    const float* ln2_g   = (const float*)d_in[14];
    const float* ln2_b   = (const float*)d_in[15];
    const float* ca_Wq   = (const float*)d_in[16];
    const float* ca_bq   = (const float*)d_in[17];
    const float* ca_Wk   = (const float*)d_in[18];
    /* ca_bk = d_in[19] unused: softmax shift-invariant */
    const float* ca_Wv   = (const float*)d_in[20];
    const float* ca_bv   = (const float*)d_in[21];
    const float* ca_Wo   = (const float*)d_in[22];
    const float* ca_bo   = (const float*)d_in[23];
    const float* ln3_g   = (const float*)d_in[24];
    const float* ln3_b   = (const float*)d_in[25];
    const float* W1      = (const float*)d_in[26];
    const float* b1      = (const float*)d_in[27];
    const float* W2      = (const float*)d_in[28];
    const float* b2      = (const float*)d_in[29];
    const int*   inds    = (const int*)d_in[30];

    char* ws = (char*)d_ws;
    size_t off = 0;
    auto alloc = [&](size_t bytes) { char* p = ws + off; off += (bytes + 1023) & ~(size_t)1023; return p; };

    unsigned short* wTproj = (unsigned short*)alloc(256 * 128 * 2);
    unsigned short* wTsaWv = (unsigned short*)alloc(256 * 256 * 2);
    unsigned short* wTsaWo = (unsigned short*)alloc(256 * 256 * 2);
    unsigned short* wTcaWq = (unsigned short*)alloc(256 * 256 * 2);
    unsigned short* wTkv   = (unsigned short*)alloc(512 * 256 * 2);
    unsigned short* wTcaWo = (unsigned short*)alloc(256 * 256 * 2);
    unsigned short* wTW1   = (unsigned short*)alloc(256 * 256 * 2);
    unsigned short* wTW2   = (unsigned short*)alloc(256 * 256 * 2);
    float*          penc0  = (float*)alloc(256 * 4);
    float*          bp2    = (float*)alloc(256 * 4);
    unsigned short* srcb   = (unsigned short*)alloc((size_t)NROW_S * 128 * 2);
    unsigned short* qfb    = (unsigned short*)alloc((size_t)NROW_Q * 128 * 2);
    unsigned short* srcp   = (unsigned short*)alloc((size_t)NROW_S * 256 * 2);
    float*          qx     = (float*)alloc((size_t)NROW_Q * 256 * 4);
    unsigned short* hbuf   = (unsigned short*)alloc((size_t)NROW_Q * 256 * 2);
    unsigned short* tbuf   = (unsigned short*)alloc((size_t)NROW_Q * 256 * 2);
    float*          xbuf   = (float*)alloc((size_t)NROW_Q * 256 * 4);
    unsigned short* qbuf   = (unsigned short*)alloc((size_t)NROW_Q * 256 * 2);
    unsigned short* ctxbuf = (unsigned short*)alloc((size_t)NROW_Q * 256 * 2);
    float*          x2buf  = (float*)alloc((size_t)NROW_Q * 256 * 4);

    dim3 bl16(16, 16);
    k_prep<<<dim3(16, 16, 10), bl16, 0, stream>>>(
        W_proj, sa_Wv, sa_Wo, ca_Wq, ca_Wk, ca_Wv, ca_Wo, W1, W2, b_pos,
        wTproj, wTsaWv, wTsaWo, wTcaWq, wTkv, wTcaWo, wTW1, wTW2, penc0);
    k_scale<<<1, 256, 0, stream>>>(b_pos, bp2);

    k_cvt<<<1024, 256, 0, stream>>>(src_f, srcb, NROW_S * 128 / 4);
    k_cvt<<<1024, 256, 0, stream>>>(query_f, qfb, NROW_Q * 128 / 4);

    // src_p = src @ W_proj + b_proj  (bf16)
    k_gemm<0><<<dim3(512, 4), 256, 0, stream>>>(srcb, wTproj, b_proj, nullptr, srcp, NROW_S, 256, 128);
    // query_x = query @ W_proj + b_proj + pos_enc(0)  (f32 master)
    k_gemm<2><<<dim3(128, 4), 256, 0, stream>>>(qfb, wTproj, b_proj, penc0, qx, NROW_Q, 256, 128);

    // self-attention block (seq len 1): x = qx + (ln1(qx)@saWv+bv)@saWo+bo
    k_ln<<<4096, 256, 0, stream>>>(qx, ln1_g, ln1_b, hbuf);
    k_gemm<0><<<dim3(128, 4), 256, 0, stream>>>(hbuf, wTsaWv, sa_bv, nullptr, tbuf, NROW_Q, 256, 256);
    k_gemm<3><<<dim3(128, 4), 256, 0, stream>>>(tbuf, wTsaWo, sa_bo, qx, xbuf, NROW_Q, 256, 256);

    // cross-attention (fused gather+cook+projection+softmax+ctx)
    k_ln<<<4096, 256, 0, stream>>>(xbuf, ln2_g, ln2_b, hbuf);
    k_gemm<0><<<dim3(128, 4), 256, 0, stream>>>(hbuf, wTcaWq, ca_bq, nullptr, qbuf, NROW_Q, 256, 256);
    k_attn3<<<4096, 256, 0, stream>>>(srcp, qbuf, inds, s_pts, q_pts, W_pos, bp2, wTkv, ca_bv, ctxbuf);
    k_gemm<3><<<dim3(128, 4), 256, 0, stream>>>(ctxbuf, wTcaWo, ca_bo, xbuf, x2buf, NROW_Q, 256, 256);

    // feed-forward + nan_to_num -> d_out (f32)
    k_ln<<<4096, 256, 0, stream>>>(x2buf, ln3_g, ln3_b, hbuf);
    k_gemm<1><<<dim3(128, 4), 256, 0, stream>>>(hbuf, wTW1, b1, nullptr, tbuf, NROW_Q, 256, 256);
    k_gemm<4><<<dim3(128, 4), 256, 0, stream>>>(tbuf, wTW2, b2, x2buf, d_out, NROW_Q, 256, 256);

    (void)in_sizes; (void)n_in; (void)out_size; (void)ws_size;
}

// Round 10
// 394.210 us; speedup vs baseline: 2.9520x; 1.2849x over previous
//
#include <hip/hip_runtime.h>
#include <hip/hip_bf16.h>
#include <math.h>
#include <stdint.h>

// ---------------- types & helpers ----------------
typedef __attribute__((ext_vector_type(8))) short short8;   // 8 x bf16 (MFMA A/B frag)
typedef __attribute__((ext_vector_type(4))) float floatx4;  // MFMA C/D frag

#define DEVI __device__ __forceinline__

DEVI float b2f(unsigned short u) {
    union { unsigned int i; float f; } v; v.i = ((unsigned int)u) << 16; return v.f;
}
DEVI unsigned short f2b(float f) {   // RNE f32 -> bf16
    unsigned int x = __float_as_uint(f);
    unsigned int r = (x + 0x7fffu + ((x >> 16) & 1u)) >> 16;
    return (unsigned short)r;
}

// global -> LDS direct (16B per lane). LDS dest must be wave-uniform base + lane*16.
#define GLD16(gp, lp)                                                            \
    __builtin_amdgcn_global_load_lds(                                            \
        (__attribute__((address_space(1))) unsigned int*)(gp),                   \
        (__attribute__((address_space(3))) unsigned int*)(lp), 16, 0, 0)

static constexpr int NQ = 4096, NS = 16384;
static constexpr int NROW_Q = 4 * NQ;   // 16384 query rows
static constexpr int NROW_S = 4 * NS;   // 65536 source rows
static constexpr float INV2PI = 0.15915494309189535f;

// ---------------- prep: transpose weights to bf16 [N][K], penc0 ----------------
__global__ void k_prep(const float* Wproj, const float* saWv, const float* saWo,
                       const float* caWq, const float* caWk, const float* caWv,
                       const float* caWo, const float* W1, const float* W2,
                       const float* b_pos,
                       unsigned short* wTproj, unsigned short* wTsaWv, unsigned short* wTsaWo,
                       unsigned short* wTcaWq, unsigned short* wTkv, unsigned short* wTcaWo,
                       unsigned short* wTW1, unsigned short* wTW2, float* penc0)
{
    int z = blockIdx.z;
    if (z == 9) {   // penc0[c] = pos_enc(0): [0,0,0, cos(b_pos)]
        if (blockIdx.x == 0 && blockIdx.y == 0) {
            int c = threadIdx.y * 16 + threadIdx.x;
            float v = 0.f;
            if (c >= 3) {
                float rev = b_pos[c - 3] * INV2PI;
                rev -= floorf(rev);
                v = __builtin_amdgcn_cosf(rev);
            }
            penc0[c] = v;
        }
        return;
    }
    int n = blockIdx.x * 16 + threadIdx.x;   // output row (orig col)
    int k = blockIdx.y * 16 + threadIdx.y;   // output col (orig row)
    const float* src; unsigned short* dst; int K = 256;
    switch (z) {
        case 0: src = Wproj; dst = wTproj; K = 128; break;
        case 1: src = saWv;  dst = wTsaWv; break;
        case 2: src = saWo;  dst = wTsaWo; break;
        case 3: src = caWq;  dst = wTcaWq; break;
        case 4: src = caWk;  dst = wTkv;   break;
        case 5: src = caWv;  dst = wTkv + 256 * 256; break;
        case 6: src = caWo;  dst = wTcaWo; break;
        case 7: src = W1;    dst = wTW1;   break;
        default: src = W2;   dst = wTW2;   break;
    }
    if (k < K) dst[(size_t)n * K + k] = f2b(src[(size_t)k * 256 + n]);
}

// scale b_pos by 1/2pi (W_pos must stay UNSCALED: revolutions = x.W + b/2pi)
__global__ void k_scale(const float* b_pos, float* bp2)
{
    int i = blockIdx.x * blockDim.x + threadIdx.x;
    if (i < 253) bp2[i] = b_pos[i] * INV2PI;
}

// ---------------- f32 -> bf16 convert ----------------
__global__ void k_cvt(const float* in, unsigned short* out, int n4)
{
    int i = blockIdx.x * blockDim.x + threadIdx.x;
    int stride = gridDim.x * blockDim.x;
    for (; i < n4; i += stride) {
        float4 v = ((const float4*)in)[i];
        unsigned long long p =
              (unsigned long long)f2b(v.x)
            | ((unsigned long long)f2b(v.y) << 16)
            | ((unsigned long long)f2b(v.z) << 32)
            | ((unsigned long long)f2b(v.w) << 48);
        ((unsigned long long*)out)[i] = p;
    }
}

// ---------------- MFMA GEMM: out[M][N] = A[M][K](bf16) @ BT[N][K]^T + epilogue ----------------
// EPI: 0 = bf16 out, +bias            1 = bf16 out, +bias, relu
//      4 = f32 out, +bias +extra[row,col], nan_to_num
template<int EPI>
__global__ __launch_bounds__(256, 2)
void k_gemm(const unsigned short* A, const unsigned short* BT, const float* bias,
            const float* extra, void* outp, int M, int N, int K)
{
    __shared__ alignas(16) unsigned short lA[128 * 64];  // [128 rows][64 k], swizzled
    __shared__ alignas(16) unsigned short lB[64 * 64];   // [64 rows][64 k], swizzled
    const int tid = threadIdx.x;
    const int wave = tid >> 6, lane = tid & 63;
    const int m0 = blockIdx.x * 128, n0 = blockIdx.y * 64;
    const int wm = (wave >> 1) * 64, wn = (wave & 1) * 32;
    floatx4 acc[4][2] = {};

    for (int kt = 0; kt < K; kt += 64) {
        __syncthreads();
        #pragma unroll
        for (int c = 0; c < 4; ++c) {   // stage A tile 16KB
            int o = (tid + c * 256) * 16;
            int row = o >> 7, inner = o & 127;
            int srk = inner ^ ((row & 7) << 4);
            GLD16((const char*)A + ((size_t)(m0 + row) * K + kt) * 2 + srk, (char*)lA + o);
        }
        #pragma unroll
        for (int c = 0; c < 2; ++c) {   // stage B tile 8KB
            int o = (tid + c * 256) * 16;
            int row = o >> 7, inner = o & 127;
            int srk = inner ^ ((row & 7) << 4);
            GLD16((const char*)BT + ((size_t)(n0 + row) * K + kt) * 2 + srk, (char*)lB + o);
        }
        __syncthreads();
        #pragma unroll
        for (int kc = 0; kc < 2; ++kc) {
            const int kb = kc * 64 + ((lane >> 4) << 4);
            short8 bf[2];
            #pragma unroll
            for (int nf = 0; nf < 2; ++nf) {
                int nn = wn + nf * 16 + (lane & 15);
                bf[nf] = *(const short8*)((const char*)lB + nn * 128 + (kb ^ ((nn & 7) << 4)));
            }
            #pragma unroll
            for (int mf = 0; mf < 4; ++mf) {
                int rr = wm + mf * 16 + (lane & 15);
                short8 af = *(const short8*)((const char*)lA + rr * 128 + (kb ^ ((rr & 7) << 4)));
                acc[mf][0] = __builtin_amdgcn_mfma_f32_16x16x32_bf16(af, bf[0], acc[mf][0], 0, 0, 0);
                acc[mf][1] = __builtin_amdgcn_mfma_f32_16x16x32_bf16(af, bf[1], acc[mf][1], 0, 0, 0);
            }
        }
    }
    #pragma unroll
    for (int mf = 0; mf < 4; ++mf)
        #pragma unroll
        for (int nf = 0; nf < 2; ++nf)
            #pragma unroll
            for (int r = 0; r < 4; ++r) {
                int row = m0 + wm + mf * 16 + ((lane >> 4) << 2) + r;
                int col = n0 + wn + nf * 16 + (lane & 15);
                float v = acc[mf][nf][r] + bias[col];
                if (EPI == 4) v += extra[(size_t)row * N + col];
                if (EPI == 1) v = fmaxf(v, 0.f);
                if (EPI == 4) {
                    if (isnan(v)) v = 0.f;
                    else if (isinf(v)) v = v > 0.f ? 3.402823466e38f : -3.402823466e38f;
                }
                if (EPI == 0 || EPI == 1)
                    ((unsigned short*)outp)[(size_t)row * N + col] = f2b(v);
                else
                    ((float*)outp)[(size_t)row * N + col] = v;
            }
}

// ---------------- fused GEMM + row-LayerNorm epilogue ----------------
// tile 64 rows x 256 cols (full row per block -> in-wave LN). 4 waves, wave w = rows w*16..w*16+15.
// EPI2: 0 = v = acc+bias+extra[col] (penc0)   1 = v = acc+bias+extra[row][col] (residual)
// writes: outf[row][col] = v (f32 master)  AND  outb[row][col] = bf16 LN(v) with g,b.
template<int EPI2>
__global__ __launch_bounds__(256, 2)
void k_gemm_ln(const unsigned short* A, const unsigned short* BT, const float* bias,
               const float* extra, const float* lng, const float* lnb,
               float* outf, unsigned short* outb, int M, int K)
{
    __shared__ alignas(16) unsigned short lA[64 * 64];    // 8 KB
    __shared__ alignas(16) unsigned short lB[256 * 64];   // 32 KB
    const int tid = threadIdx.x, wave = tid >> 6, lane = tid & 63;
    const int l15 = lane & 15, lg = lane >> 4;
    const int m0 = blockIdx.x * 64;
    floatx4 acc[16] = {};

    for (int kt = 0; kt < K; kt += 64) {
        __syncthreads();
        #pragma unroll
        for (int c = 0; c < 2; ++c) {   // stage A 8KB
            int o = (tid + c * 256) * 16;
            int row = o >> 7, inner = o & 127;
            int srk = inner ^ ((row & 7) << 4);
            GLD16((const char*)A + ((size_t)(m0 + row) * K + kt) * 2 + srk, (char*)lA + o);
        }
        #pragma unroll
        for (int c = 0; c < 8; ++c) {   // stage B 32KB (all 256 n-rows)
            int o = (tid + c * 256) * 16;
            int row = o >> 7, inner = o & 127;
            int srk = inner ^ ((row & 7) << 4);
            GLD16((const char*)BT + ((size_t)row * K + kt) * 2 + srk, (char*)lB + o);
        }
        __syncthreads();
        #pragma unroll
        for (int kc = 0; kc < 2; ++kc) {
            const int kb = kc * 64 + (lg << 4);
            int rr = wave * 16 + l15;
            short8 af = *(const short8*)((const char*)lA + rr * 128 + (kb ^ ((rr & 7) << 4)));
            #pragma unroll
            for (int nf = 0; nf < 16; ++nf) {
                int nn = nf * 16 + l15;
                short8 bf = *(const short8*)((const char*)lB + nn * 128 + (kb ^ ((nn & 7) << 4)));
                acc[nf] = __builtin_amdgcn_mfma_f32_16x16x32_bf16(af, bf, acc[nf], 0, 0, 0);
            }
        }
    }

    // epilogue: lane holds rows m0 + wave*16 + lg*4 + r (r=0..3), col = nf*16 + l15
    #pragma unroll
    for (int nf = 0; nf < 16; ++nf) {
        int col = nf * 16 + l15;
        float bi = bias[col] + (EPI2 == 0 ? extra[col] : 0.f);
        #pragma unroll
        for (int r = 0; r < 4; ++r) {
            int row = m0 + wave * 16 + lg * 4 + r;
            float v = acc[nf][r] + bi;
            if (EPI2 == 1) v += extra[(size_t)row * 256 + col];
            acc[nf][r] = v;
            outf[(size_t)row * 256 + col] = v;
        }
    }
    float mean[4], inv[4];
    #pragma unroll
    for (int r = 0; r < 4; ++r) {
        float s = 0.f;
        #pragma unroll
        for (int nf = 0; nf < 16; ++nf) s += acc[nf][r];
        #pragma unroll
        for (int t = 1; t <= 8; t <<= 1) s += __shfl_xor(s, t);
        mean[r] = s * (1.f / 256.f);
        float q = 0.f;
        #pragma unroll
        for (int nf = 0; nf < 16; ++nf) { float d = acc[nf][r] - mean[r]; q += d * d; }
        #pragma unroll
        for (int t = 1; t <= 8; t <<= 1) q += __shfl_xor(q, t);
        inv[r] = 1.0f / sqrtf(q * (1.f / 256.f) + 1e-5f);
    }
    #pragma unroll
    for (int nf = 0; nf < 16; ++nf) {
        int col = nf * 16 + l15;
        float g = lng[col], b = lnb[col];
        #pragma unroll
        for (int r = 0; r < 4; ++r) {
            int row = m0 + wave * 16 + lg * 4 + r;
            outb[(size_t)row * 256 + col] = f2b((acc[nf][r] - mean[r]) * inv[r] * g + b);
        }
    }
}

// ---------------- fused neighbor attention (r3-proven + qv/bv preload hoist) ----------------
// block = 4 queries (64 neighbor rows), 256 threads (4 waves). 3 blocks/CU.
// P1: prefetch-all gather + pos-enc -> nx LDS (bf16, swizzled); qv/bvv preloaded. ONE barrier.
// P2: kk = nx @ Wk, acc[4][4] in regs. P3: softmax (in-register, shfl). P4: vv + ctx.
__global__ __launch_bounds__(256, 3)
void k_attn(const unsigned short* srcp, const unsigned short* qb, const int* inds,
            const float* s_pts, const float* q_pts, const float* W_pos, const float* bp2,
            const unsigned short* wTkv, const float* bv, unsigned short* ctx)
{
    __shared__ alignas(16) unsigned short nx[64 * 256];   // 32 KB, XOR-swizzled rows
    __shared__ alignas(16) float att_lds[4 * 16 * 16];    // 4 KB [q][h][k]
    __shared__ alignas(16) float dist_lds[64];            // (dist/RADIUS)^2
    const int tid = threadIdx.x, wave = tid >> 6, lane = tid & 63;
    const int qbase = blockIdx.x * 4;
    const int l15 = lane & 15, lg = lane >> 4;

    // ---- preload q fragments & bias (independent; fly with the gather) ----
    float qv[4][4], bvv[4];
    #pragma unroll
    for (int mf = 0; mf < 4; ++mf)
        #pragma unroll
        for (int nf = 0; nf < 4; ++nf)
            qv[mf][nf] = b2f(qb[(size_t)(qbase + mf) * 256 + (wave * 4 + nf) * 16 + l15]) * 0.25f;
    #pragma unroll
    for (int nf = 0; nf < 4; ++nf) bvv[nf] = bv[(wave * 4 + nf) * 16 + l15];

    // ---- P1: gather + positional encoding (loads issued first, cos hides latency) ----
    {
        int r = tid >> 2, sub = tid & 3;          // row 0..63, 64-col chunk
        int qi = qbase + (r >> 4);
        int bb = qi >> 12;                        // / NQ
        int k = r & 15;
        int raw = inds[((size_t)qi << 4) + k];
        int idx = raw % (NS + 1); if (idx < 0) idx += NS + 1;
        bool shadow = (idx == NS);
        const int c0 = sub * 64;
        // issue ALL 8 feature loads up-front (shadow rows read row 0, masked later)
        const unsigned short* srow = srcp + ((size_t)bb * NS + (shadow ? 0 : idx)) * 256 + c0;
        short8 sv[8];
        #pragma unroll
        for (int j = 0; j < 8; ++j) sv[j] = *(const short8*)(srow + j * 8);

        float px = q_pts[(size_t)qi * 3], py = q_pts[(size_t)qi * 3 + 1], pz = q_pts[(size_t)qi * 3 + 2];
        float sx, sy, sz;
        if (shadow) { sx = sy = sz = 1e6f; }
        else {
            const float* sp = s_pts + ((size_t)bb * NS + idx) * 3;
            sx = sp[0]; sy = sp[1]; sz = sp[2];
        }
        float tx = (sx - px) * 0.25f, ty = (sy - py) * 0.25f, tz = (sz - pz) * 0.25f;
        if (sub == 0) dist_lds[r] = tx * tx + ty * ty + tz * tz;   // >1 <=> dist>RADIUS

        #pragma unroll
        for (int cc = 0; cc < 64; cc += 8) {
            short8 vals;
            #pragma unroll
            for (int j = 0; j < 8; ++j) {
                int c = c0 + cc + j;
                float pe;
                if (c == 0) pe = tx;
                else if (c == 1) pe = ty;
                else if (c == 2) pe = tz;
                else {
                    int jj = c - 3;
                    float rev = fmaf(tx, W_pos[jj],
                                fmaf(ty, W_pos[253 + jj],
                                fmaf(tz, W_pos[506 + jj], bp2[jj])));
                    rev -= floorf(rev);
                    pe = __builtin_amdgcn_cosf(rev);
                }
                float sval = shadow ? 0.f : b2f((unsigned short)sv[cc / 8][j]);
                vals[j] = (short)f2b(sval + pe);
            }
            int byte = (c0 + cc) * 2;
            *(short8*)((char*)nx + r * 512 + (byte ^ ((r & 7) << 4))) = vals;
        }
    }
    __syncthreads();   // the ONLY block-wide barrier

    const int wn = wave * 64;   // this wave's 64 output cols = heads 4w..4w+3
    floatx4 acc[4][4];

    // ---- P2: kk = nx @ Wk ----
    #pragma unroll
    for (int mf = 0; mf < 4; ++mf)
        #pragma unroll
        for (int nf = 0; nf < 4; ++nf) acc[mf][nf] = floatx4{0.f, 0.f, 0.f, 0.f};

    #pragma unroll 2
    for (int kt = 0; kt < 8; ++kt) {
        const int kb = kt * 64 + (lg << 4);
        short8 bfr[4];
        #pragma unroll
        for (int nf = 0; nf < 4; ++nf) {
            int nn = wn + nf * 16 + l15;
            bfr[nf] = *(const short8*)((const char*)wTkv + (size_t)nn * 512 + kt * 64 + (lg << 4));
        }
        #pragma unroll
        for (int mf = 0; mf < 4; ++mf) {
            int rr = mf * 16 + l15;
            short8 af = *(const short8*)((const char*)nx + rr * 512 + (kb ^ ((rr & 7) << 4)));
            #pragma unroll
            for (int nf = 0; nf < 4; ++nf)
                acc[mf][nf] = __builtin_amdgcn_mfma_f32_16x16x32_bf16(af, bfr[nf], acc[mf][nf], 0, 0, 0);
        }
    }

    // ---- P3: scores + softmax (in-register) ----
    // acc[mf][nf][rr] = kk[k = lg*4+rr][h*16+dd], h = wave*4+nf, dd = l15
    {
        #pragma unroll
        for (int mf = 0; mf < 4; ++mf) {
            float4 d4 = *(const float4*)&dist_lds[mf * 16 + lg * 4];   // broadcast read
            float dd4[4] = {d4.x, d4.y, d4.z, d4.w};
            #pragma unroll
            for (int nf = 0; nf < 4; ++nf) {
                float s[4];
                #pragma unroll
                for (int rr = 0; rr < 4; ++rr) s[rr] = acc[mf][nf][rr] * qv[mf][nf];
                #pragma unroll
                for (int t = 1; t <= 8; t <<= 1)
                    #pragma unroll
                    for (int rr = 0; rr < 4; ++rr) s[rr] += __shfl_xor(s[rr], t);
                #pragma unroll
                for (int rr = 0; rr < 4; ++rr)
                    s[rr] = (dd4[rr] > 1.0f) ? -1e9f : s[rr];
                float m = fmaxf(fmaxf(s[0], s[1]), fmaxf(s[2], s[3]));
                m = fmaxf(m, __shfl_xor(m, 16));
                m = fmaxf(m, __shfl_xor(m, 32));
                float p[4], su = 0.f;
                #pragma unroll
                for (int rr = 0; rr < 4; ++rr) { p[rr] = __expf(s[rr] - m); su += p[rr]; }
                su += __shfl_xor(su, 16);
                su += __shfl_xor(su, 32);
                float inv = __builtin_amdgcn_rcpf(su);
                if (l15 == 0) {
                    float4 a4 = {p[0] * inv, p[1] * inv, p[2] * inv, p[3] * inv};
                    *(float4*)&att_lds[(mf * 16 + wave * 4 + nf) * 16 + lg * 4] = a4;
                }
            }
        }
    }

    // ---- P4: vv = nx @ Wv (reuse acc), then ctx = att . vv ----
    #pragma unroll
    for (int mf = 0; mf < 4; ++mf)
        #pragma unroll
        for (int nf = 0; nf < 4; ++nf) acc[mf][nf] = floatx4{0.f, 0.f, 0.f, 0.f};

    #pragma unroll 2
    for (int kt = 0; kt < 8; ++kt) {
        const int kb = kt * 64 + (lg << 4);
        short8 bfr[4];
        #pragma unroll
        for (int nf = 0; nf < 4; ++nf) {
            int nn = 256 + wn + nf * 16 + l15;      // Wv half of wTkv
            bfr[nf] = *(const short8*)((const char*)wTkv + (size_t)nn * 512 + kt * 64 + (lg << 4));
        }
        #pragma unroll
        for (int mf = 0; mf < 4; ++mf) {
            int rr = mf * 16 + l15;
            short8 af = *(const short8*)((const char*)nx + rr * 512 + (kb ^ ((rr & 7) << 4)));
            #pragma unroll
            for (int nf = 0; nf < 4; ++nf)
                acc[mf][nf] = __builtin_amdgcn_mfma_f32_16x16x32_bf16(af, bfr[nf], acc[mf][nf], 0, 0, 0);
        }
    }

    {
        #pragma unroll
        for (int mf = 0; mf < 4; ++mf)
            #pragma unroll
            for (int nf = 0; nf < 4; ++nf) {
                float4 a4 = *(const float4*)&att_lds[(mf * 16 + wave * 4 + nf) * 16 + lg * 4];
                float o = a4.x * acc[mf][nf][0];
                o = fmaf(a4.y, acc[mf][nf][1], o);
                o = fmaf(a4.z, acc[mf][nf][2], o);
                o = fmaf(a4.w, acc[mf][nf][3], o);
                o += __shfl_xor(o, 16);
                o += __shfl_xor(o, 32);
                o += bvv[nf];
                if (lane < 16)
                    ctx[(size_t)(qbase + mf) * 256 + (wave * 4 + nf) * 16 + lane] = f2b(o);
            }
    }
}

// ---------------- host launcher ----------------
extern "C" void kernel_launch(void* const* d_in, const int* in_sizes, int n_in,
                              void* d_out, int out_size, void* d_ws, size_t ws_size,
                              hipStream_t stream)
{
    const float* q_pts   = (const float*)d_in[0];
    const float* s_pts   = (const float*)d_in[1];
    const float* src_f   = (const float*)d_in[2];
    const float* query_f = (const float*)d_in[3];
    const float* W_proj  = (const float*)d_in[4];
    const float* b_proj  = (const float*)d_in[5];
    const float* W_pos   = (const float*)d_in[6];
    const float* b_pos   = (const float*)d_in[7];
    const float* ln1_g   = (const float*)d_in[8];
    const float* ln1_b   = (const float*)d_in[9];
    const float* sa_Wv   = (const float*)d_in[10];
    const float* sa_bv   = (const float*)d_in[11];
    const float* sa_Wo   = (const float*)d_in[12];
    const float* sa_bo   = (const float*)d_in[13];
    const float* ln2_g   = (const float*)d_in[14];
    const float* ln2_b   = (const float*)d_in[15];
    const float* ca_Wq   = (const float*)d_in[16];
    const float* ca_bq   = (const float*)d_in[17];
    const float* ca_Wk   = (const float*)d_in[18];
    /* ca_bk = d_in[19] unused: softmax shift-invariant */
    const float* ca_Wv   = (const float*)d_in[20];
    const float* ca_bv   = (const float*)d_in[21];
    const float* ca_Wo   = (const float*)d_in[22];
    const float* ca_bo   = (const float*)d_in[23];
    const float* ln3_g   = (const float*)d_in[24];
    const float* ln3_b   = (const float*)d_in[25];
    const float* W1      = (const float*)d_in[26];
    const float* b1      = (const float*)d_in[27];
    const float* W2      = (const float*)d_in[28];
    const float* b2      = (const float*)d_in[29];
    const int*   inds    = (const int*)d_in[30];

    char* ws = (char*)d_ws;
    size_t off = 0;
    auto alloc = [&](size_t bytes) { char* p = ws + off; off += (bytes + 1023) & ~(size_t)1023; return p; };

    unsigned short* wTproj = (unsigned short*)alloc(256 * 128 * 2);
    unsigned short* wTsaWv = (unsigned short*)alloc(256 * 256 * 2);
    unsigned short* wTsaWo = (unsigned short*)alloc(256 * 256 * 2);
    unsigned short* wTcaWq = (unsigned short*)alloc(256 * 256 * 2);
    unsigned short* wTkv   = (unsigned short*)alloc(512 * 256 * 2);
    unsigned short* wTcaWo = (unsigned short*)alloc(256 * 256 * 2);
    unsigned short* wTW1   = (unsigned short*)alloc(256 * 256 * 2);
    unsigned short* wTW2   = (unsigned short*)alloc(256 * 256 * 2);
    float*          penc0  = (float*)alloc(256 * 4);
    float*          bp2    = (float*)alloc(256 * 4);
    unsigned short* srcb   = (unsigned short*)alloc((size_t)NROW_S * 128 * 2);
    unsigned short* qfb    = (unsigned short*)alloc((size_t)NROW_Q * 128 * 2);
    unsigned short* srcp   = (unsigned short*)alloc((size_t)NROW_S * 256 * 2);
    float*          qx     = (float*)alloc((size_t)NROW_Q * 256 * 4);
    unsigned short* hbuf   = (unsigned short*)alloc((size_t)NROW_Q * 256 * 2);
    unsigned short* tbuf   = (unsigned short*)alloc((size_t)NROW_Q * 256 * 2);
    float*          xbuf   = (float*)alloc((size_t)NROW_Q * 256 * 4);
    unsigned short* qbuf   = (unsigned short*)alloc((size_t)NROW_Q * 256 * 2);
    unsigned short* ctxbuf = (unsigned short*)alloc((size_t)NROW_Q * 256 * 2);
    float*          x2buf  = (float*)alloc((size_t)NROW_Q * 256 * 4);

    dim3 bl16(16, 16);
    k_prep<<<dim3(16, 16, 10), bl16, 0, stream>>>(
        W_proj, sa_Wv, sa_Wo, ca_Wq, ca_Wk, ca_Wv, ca_Wo, W1, W2, b_pos,
        wTproj, wTsaWv, wTsaWo, wTcaWq, wTkv, wTcaWo, wTW1, wTW2, penc0);
    k_scale<<<1, 256, 0, stream>>>(b_pos, bp2);

    k_cvt<<<1024, 256, 0, stream>>>(src_f, srcb, NROW_S * 128 / 4);
    k_cvt<<<1024, 256, 0, stream>>>(query_f, qfb, NROW_Q * 128 / 4);

    // src_p = src @ W_proj + b_proj  (bf16)
    k_gemm<0><<<dim3(512, 4), 256, 0, stream>>>(srcb, wTproj, b_proj, nullptr, srcp, NROW_S, 256, 128);
    // query_x = query @ W_proj + b_proj + pos_enc(0); qx f32 + hbuf = LN1(qx)
    k_gemm_ln<0><<<256, 256, 0, stream>>>(qfb, wTproj, b_proj, penc0, ln1_g, ln1_b,
                                          qx, hbuf, NROW_Q, 128);

    // self-attention block (seq len 1): xbuf = qx + (hbuf@saWv+bv)@saWo+bo ; hbuf = LN2(xbuf)
    k_gemm<0><<<dim3(128, 4), 256, 0, stream>>>(hbuf, wTsaWv, sa_bv, nullptr, tbuf, NROW_Q, 256, 256);
    k_gemm_ln<1><<<256, 256, 0, stream>>>(tbuf, wTsaWo, sa_bo, qx, ln2_g, ln2_b,
                                          xbuf, hbuf, NROW_Q, 256);

    // cross-attention: qbuf = hbuf@caWq+bq ; attn ; x2buf = xbuf + ctx@caWo+bo ; hbuf = LN3
    k_gemm<0><<<dim3(128, 4), 256, 0, stream>>>(hbuf, wTcaWq, ca_bq, nullptr, qbuf, NROW_Q, 256, 256);
    k_attn<<<4096, 256, 0, stream>>>(srcp, qbuf, inds, s_pts, q_pts, W_pos, bp2, wTkv, ca_bv, ctxbuf);
    k_gemm_ln<1><<<256, 256, 0, stream>>>(ctxbuf, wTcaWo, ca_bo, xbuf, ln3_g, ln3_b,
                                          x2buf, hbuf, NROW_Q, 256);

    // feed-forward + nan_to_num -> d_out (f32)
    k_gemm<1><<<dim3(128, 4), 256, 0, stream>>>(hbuf, wTW1, b1, nullptr, tbuf, NROW_Q, 256, 256);
    k_gemm<4><<<dim3(128, 4), 256, 0, stream>>>(tbuf, wTW2, b2, x2buf, d_out, NROW_Q, 256, 256);

    (void)in_sizes; (void)n_in; (void)out_size; (void)ws_size;
}